// Round 1
// 61.181 us; speedup vs baseline: 1.0128x; 1.0128x over previous
//
#include <hip/hip_runtime.h>
#include <math.h>

// SpikeMLP: 2-layer spiking MLP, batch=128, in=800, hid=128, out=10.
//
// Trajectory: R3 66us (1 wave/CU latency-bound) -> R5 two-kernel split ->
// R6 fused spin-wait REGRESSED (cross-XCD fences, 77us kernel; reverted) ->
// R7 62.1us (1024 blocks, 16 lanes/neuron, closed-form crossing) ->
// R8 2048 blocks/32 lanes REGRESSED (64.0us) -> R9 revert to R7 ->
// R10 THIS: single-kernel per-batch fusion. Key insight: out[b,o] depends
// only on hs[b,:], so one block per batch makes layer 2 BLOCK-LOCAL —
// __syncthreads() instead of R6's grid-wide spin-wait/fences. Removes the
// second dispatch (+its ~3-5us launch gap), the d_ws round-trip entirely.
//
// Budget: ~40us harness ws-poison fill (256MB @ 6.7TB/s, untouchable) +
// ~10us other harness reset nodes/gaps + ~12us our k1+gap+k2 in R7.
// Fused kernel target ~3-5us -> predicted total ~55-58us.
//
// Layer-1 math (verified R3-R8): for t>=256 (the only finite-threshold
// steps) every finite ti < 1.0 <= t*DT, so mem(t) = t*DT*S - A with
// S=sum(W1[n,i]), A=sum(ti*W1[n,i]) over finite ti. mem(511)>0 gates
// spiking; first crossing of mem(t) > (511-t)*DT is closed-form:
// t > (A+511*DT)/(DT*(S+1)) for S+1>0, else t=256.
// Layer-2: v(t) = t*S2 - A2 linear (no relu) -> endpoint guard, faithful
// per-step loop only if v can approach 20. "No spike" sentinel = 1e30f
// (bf16-finite; harness compares in bf16 -> FLT_MAX/inf gives nan-fail).

#define DT (1.0f / 256.0f)
#define NSTEP 256
#define TSTEPS 512
#define IN_DIM 800
#define HID 128
#define OUT_DIM 10
#define NOSPIKE 1e30f

// ---------------- fused kernel: one block per batch row -------------------
// 128 blocks x 1024 threads. Layer 1: neuron n = tid>>3, slice s = tid&7,
// lane covers i = k*32 + s*4 (+3), k = 0..24 (25*32 = 800 exact, no tail).
// Layer 2: first 10 waves, o = tid>>6, j = tid&63; hs read from LDS.
__global__ __launch_bounds__(1024) void spike_fused(
    const float* __restrict__ x,    // [128, 800]
    const float* __restrict__ W1,   // [128, 800]
    const float* __restrict__ W2,   // [10, 128]
    float* __restrict__ out)        // [128, 10]
{
    const int b   = blockIdx.x;
    const int tid = threadIdx.x;
    const int n   = tid >> 3;              // hidden neuron 0..127
    const int s   = tid & 7;               // slice 0..7

    __shared__ __align__(16) float xm[IN_DIM];   // masked x: ti if finite else 0
    __shared__ __align__(16) float mk[IN_DIM];   // mask:     1  if finite else 0
    __shared__ float hs_sh[HID];                 // hidden spike times

    // Preload W2 fragment into registers for layer 2 (hides L2 latency
    // under layer-1 compute; only first 640 threads participate later).
    float w2a = 0.0f, w2b = 0.0f;
    if (tid < 640) {
        const int o = tid >> 6;
        const int j = tid & 63;
        const float* w2 = W2 + (size_t)o * HID;
        w2a = w2[j];
        w2b = w2[j + 64];
    }

    // stage x row into LDS (coalesced; one element per thread, 800 < 1024)
    const float* xr = x + (size_t)b * IN_DIM;
    if (tid < IN_DIM) {
        float xi = xr[tid];
        float m  = (xi != 1.0f) ? 1.0f : 0.0f;
        xm[tid] = m * xi;
        mk[tid] = m;
    }
    __syncthreads();

    // ---- layer 1: S = sum W1[n,i]*m, A = sum W1[n,i]*ti*m ----
    const float* wr = W1 + (size_t)n * IN_DIM;
    float S = 0.0f;
    float A = 0.0f;
#pragma unroll
    for (int k = 0; k < 25; ++k) {                 // 25 x 32 = 800 elems
        const int i = k * 32 + s * 4;
        float4 wv = *(const float4*)(wr + i);
        float4 xv = *(const float4*)(&xm[i]);
        float4 mv = *(const float4*)(&mk[i]);
        S = fmaf(mv.x, wv.x, S);  A = fmaf(xv.x, wv.x, A);
        S = fmaf(mv.y, wv.y, S);  A = fmaf(xv.y, wv.y, A);
        S = fmaf(mv.z, wv.z, S);  A = fmaf(xv.z, wv.z, A);
        S = fmaf(mv.w, wv.w, S);  A = fmaf(xv.w, wv.w, A);
    }
    // reduce across the 8 slices (contiguous lanes in the wave)
    S += __shfl_xor(S, 1);  A += __shfl_xor(A, 1);
    S += __shfl_xor(S, 2);  A += __shfl_xor(A, 2);
    S += __shfl_xor(S, 4);  A += __shfl_xor(A, 4);

    if (s == 0) {
        // first t in [256,511] with t*DT*S - A > (511-t)*DT, given
        // mem(511) > 0; closed form: t > (A + 511*DT) / (DT*(S+1)).
        float h;
        float mem_last = fmaf(511.0f * DT, S, -A);
        if (!(mem_last > 0.0f)) {
            h = 1.0f;                        // no spike -> sentinel 1.0
        } else {
            float Sp = S + 1.0f;
            int tf;
            if (!(Sp > 0.0f)) {
                tf = NSTEP;                  // lhs-rhs decreasing -> first step
            } else {
                float X = (A + 511.0f * DT) / (DT * Sp);
                tf = (int)floorf(X) + 1;     // smallest integer t with t > X
                if (tf < NSTEP)      tf = NSTEP;
                if (tf > TSTEPS - 1) tf = TSTEPS - 1;
            }
            h = (float)tf * DT - 1.0f;       // exact in fp32
        }
        hs_sh[n] = h;
    }
    __syncthreads();

    // ---- layer 2: first 10 waves, one output neuron per wave ----
    if (tid < 640) {
        const int j = tid & 63;

        float hi0 = hs_sh[j];
        float hi1 = hs_sh[j + 64];
        float m0  = (hi0 != 1.0f) ? 1.0f : 0.0f;  // h==1 -> INF -> excluded
        float m1  = (hi1 != 1.0f) ? 1.0f : 0.0f;

        float S2 = 0.0f, A2 = 0.0f;
        S2 = fmaf(m0, w2a, S2);   A2 = fmaf(m0 * hi0, w2a, A2);
        S2 = fmaf(m1, w2b, S2);   A2 = fmaf(m1 * hi1, w2b, A2);

#pragma unroll
        for (int msk = 1; msk < 64; msk <<= 1) {
            S2 += __shfl_xor(S2, msk);
            A2 += __shfl_xor(A2, msk);
        }
        if (j == 0) {
            const int o = tid >> 6;
            // v(t) = t*S2 - A2, t = 1 + k*DT, k in [0,1024): linear ->
            // endpoint guard; faithful loop only if near the 20.0 threshold.
            float res = NOSPIKE;
            float v_lo = fmaf(1.0f,                S2, -A2);
            float v_hi = fmaf(1.0f + 1023.0f * DT, S2, -A2);
            if (fmaxf(v_lo, v_hi) > 19.999f) {
                for (int k = 0; k < 1024; ++k) {
                    float t = fmaf((float)k, DT, 1.0f);   // exact fp32
                    float v = fmaf(t, S2, -A2);
                    if (v > 20.0f) { res = t; break; }
                }
            }
            out[b * OUT_DIM + o] = res;
        }
    }
}

extern "C" void kernel_launch(void* const* d_in, const int* in_sizes, int n_in,
                              void* d_out, int out_size, void* d_ws, size_t ws_size,
                              hipStream_t stream) {
    const float* x  = (const float*)d_in[0];   // (128, 800)
    const float* W1 = (const float*)d_in[1];   // (128, 800)
    const float* W2 = (const float*)d_in[2];   // (10, 128)
    float* out = (float*)d_out;                // (128, 10)
    (void)d_ws; (void)ws_size;

    spike_fused<<<128, 1024, 0, stream>>>(x, W1, W2, out);
}